// Round 14
// baseline (11297.216 us; speedup 1.0000x reference)
//
#include <hip/hip_runtime.h>
#include <math.h>

#define N_NODES 100000
#define N_EDGES 3200000
#define BS 256

// ==================== setup: deterministic CSR construction ====================
// All-f32 data path, rounding-matched to the numpy reference (absmax 8.4e-11,
// rounds 7-13):
//  - bucket sums in ascending edge-id order (np.add.at semantics)
//  - products rounded separately from adds in the SpMV (np: norm*h then add.at)
//  - matmuls as ascending-k fmaf chains from 0, then one add
//  - dis = 1/sqrtf
// f64 is provably WRONG here (4 distinct f64 impls -> absmax 0.9999987).
// EVERY fp chain must stay bit-identical under refactors: parallelize only
// across independent chains (channels, rows), never within one.
//
// Perf model (r9-r13): props move ~205MB/dispatch of random 64B h-sectors;
// h (6.4-8MB) exceeds the 4MB per-XCD L2 and the 25.6MB pk stream evicts it,
// so misses go to L3/fabric (~3.4TB/s effective). unroll-4 vs unroll-2 was
// nearly flat -> not latency-bound. This round: NT on pk (protect h in L2,
// isolated A/B), fused src-sort+deg and dst-sort+packed-fill (3 fewer 12.8MB
// passes). Gathered state stays PACKED (r11 lesson: footprint > alignment).

// one pass over edges: count both src and dst buckets
__global__ void count2_kernel(const int* __restrict__ src, const int* __restrict__ dst,
                              int* __restrict__ cnt_s, int* __restrict__ cnt_d) {
    int e = blockIdx.x * blockDim.x + threadIdx.x;
    if (e < N_EDGES) {
        atomicAdd(&cnt_s[src[e]], 1);
        atomicAdd(&cnt_d[dst[e]], 1);
    }
}

__global__ void scan_partial_kernel(const int* __restrict__ cnt, int* __restrict__ bsums) {
    __shared__ int lds[256];
    int tid = threadIdx.x;
    int base = blockIdx.x * 1024 + tid * 4;
    int s = 0;
#pragma unroll
    for (int i = 0; i < 4; ++i) s += (base + i < N_NODES) ? cnt[base + i] : 0;
    lds[tid] = s;
    __syncthreads();
    for (int off = 128; off > 0; off >>= 1) {
        if (tid < off) lds[tid] += lds[tid + off];
        __syncthreads();
    }
    if (tid == 0) bsums[blockIdx.x] = lds[0];
}

__global__ void scan_bsums_kernel(int* __restrict__ bsums, int nb, int* __restrict__ total_out) {
    if (threadIdx.x == 0 && blockIdx.x == 0) {
        int acc = 0;
        for (int b = 0; b < nb; ++b) {
            int v = bsums[b];
            bsums[b] = acc;
            acc += v;
        }
        *total_out = acc;
    }
}

__global__ void scan_final_kernel(const int* __restrict__ cnt, const int* __restrict__ bsums,
                                  int* __restrict__ rp) {
    __shared__ int lds[256];
    int tid = threadIdx.x;
    int base = blockIdx.x * 1024 + tid * 4;
    int v[4];
    int ts = 0;
#pragma unroll
    for (int i = 0; i < 4; ++i) {
        v[i] = (base + i < N_NODES) ? cnt[base + i] : 0;
        ts += v[i];
    }
    lds[tid] = ts;
    __syncthreads();
    for (int off = 1; off < 256; off <<= 1) {
        int t = (tid >= off) ? lds[tid - off] : 0;
        __syncthreads();
        lds[tid] += t;
        __syncthreads();
    }
    int run = lds[tid] - ts + bsums[blockIdx.x];
#pragma unroll
    for (int i = 0; i < 4; ++i) {
        if (base + i < N_NODES) rp[base + i] = run;
        run += v[i];
    }
}

// one pass over edges: scatter edge ids into both src- and dst-keyed buckets
__global__ void fill2_kernel(const int* __restrict__ src, const int* __restrict__ dst,
                             int* __restrict__ fill_s, int* __restrict__ fill_d,
                             int* __restrict__ raw_s, int* __restrict__ raw_d) {
    int e = blockIdx.x * blockDim.x + threadIdx.x;
    if (e >= N_EDGES) return;
    int slot_s = atomicAdd(&fill_s[src[e]], 1);
    raw_s[slot_s] = e;
    int slot_d = atomicAdd(&fill_d[dst[e]], 1);
    raw_d[slot_d] = e;
}

// fused src-side: deg[n] = sum of w over row n in ASCENDING EDGE-ID order
// (selection walk, O(d^2) like the rank sort it replaces), then dis = 1/sqrtf.
__global__ void sort_deg_kernel(const int* __restrict__ rp_src, const int* __restrict__ raw,
                                const float* __restrict__ w, float* __restrict__ dis) {
#pragma clang fp contract(off)
    {
        int n = blockIdx.x * blockDim.x + threadIdx.x;
        if (n >= N_NODES) return;
        int beg = rp_src[n], end = rp_src[n + 1];
        float d = 0.f;
        int last = -1;
        for (int t = beg; t < end; ++t) {
            int mn = 0x7fffffff;
            for (int j = beg; j < end; ++j) {
                int e = raw[j];
                if (e > last && e < mn) mn = e;
            }
            d = d + w[mn];
            last = mn;
        }
        dis[n] = (d > 0.f) ? (1.0f / sqrtf(d)) : 0.f;
    }
}

// fused dst-side: rank-sort by edge id writes the packed CSR entry directly.
// packed[beg+rank] = {src, ((-dis[s]) * w) * dis[n]}  (n == dst of the row)
__global__ void sort_fill_dst_kernel(const int* __restrict__ rp_dst, const int* __restrict__ raw,
                                     const int* __restrict__ src, const float* __restrict__ w,
                                     const float* __restrict__ dis, int2* __restrict__ packed) {
#pragma clang fp contract(off)
    {
        int n = blockIdx.x * blockDim.x + threadIdx.x;
        if (n >= N_NODES) return;
        int beg = rp_dst[n], end = rp_dst[n + 1];
        float dn = dis[n];
        for (int i = beg; i < end; ++i) {
            int e = raw[i];
            int r = 0;
            for (int j = beg; j < end; ++j) r += (raw[j] < e);
            int s = src[e];
            float cw = ((-dis[s]) * w[e]) * dn;
            packed[beg + r] = make_int2(s, __float_as_int(cw));
        }
    }
}

// ==================== per-layer kernels (f32, rounding-matched) ====================

// thread per (n,co): acc[n*SACC+co] = fmaf-chain over ci of hin[n*SIN+ci]*W0[ci,co]
template <int CIN, int COUT, int SIN, int SACC>
__global__ void layer_init_kernel(const float* __restrict__ hin, const float* __restrict__ W0,
                                  float* __restrict__ acc) {
    int t = blockIdx.x * blockDim.x + threadIdx.x;
    if (t >= N_NODES * COUT) return;
    int n = t / COUT, co = t - n * COUT;
    const float* hr = hin + (size_t)n * SIN;
    float m = 0.f;
#pragma unroll
    for (int ci = 0; ci < CIN; ++ci) m = fmaf(hr[ci], W0[ci * COUT + co], m);
    acc[(size_t)n * SACC + co] = m;
}

__device__ __forceinline__ void unpack_edge(unsigned long long p, int& s, float& w) {
    s = (int)(unsigned int)(p & 0xffffffffull);          // int2.x (lo addr)
    w = __int_as_float((int)(unsigned int)(p >> 32));    // int2.y
}

// Grouped-channel prop+matmul. Block = R rows x LANES lanes; lane owns GS
// consecutive channels. Edge loop unrolled x4; pk loaded NONTEMPORAL (u64 —
// the stream is read-once per dispatch and must not evict h from L2).
// Per-channel add order strictly ascending edge id -> bit-exact vs r7.
template <int CIN, int COUT, int SIN, int SACC, int GS, int LANES, int R>
__global__ __launch_bounds__(LANES* R) void prop_mm_kernel(
    const int* __restrict__ rp, const unsigned long long* __restrict__ pk,
    const float* __restrict__ hin, const float* __restrict__ prev,
    const float* __restrict__ Wk, int rec, float* __restrict__ tx_out,
    float* __restrict__ acc) {
#pragma clang fp contract(off)
    {
        __shared__ float tls[R][LANES * GS];
        int r = threadIdx.x / LANES;
        int lane = threadIdx.x - r * LANES;
        int n = blockIdx.x * R + r;
        bool vn = (n < N_NODES);
        if (vn) {
            int c0 = lane * GS;
            float s[GS];
#pragma unroll
            for (int g = 0; g < GS; ++g) s[g] = 0.f;
            int beg = rp[n], end = rp[n + 1];
            int j = beg;
            if constexpr (GS == 4) {
                for (; j + 3 < end; j += 4) {
                    unsigned long long p0 = __builtin_nontemporal_load(&pk[j]);
                    unsigned long long p1 = __builtin_nontemporal_load(&pk[j + 1]);
                    unsigned long long p2 = __builtin_nontemporal_load(&pk[j + 2]);
                    unsigned long long p3 = __builtin_nontemporal_load(&pk[j + 3]);
                    int s0i, s1i, s2i, s3i;
                    float w0, w1, w2, w3;
                    unpack_edge(p0, s0i, w0);
                    unpack_edge(p1, s1i, w1);
                    unpack_edge(p2, s2i, w2);
                    unpack_edge(p3, s3i, w3);
                    const float4 q0 = *reinterpret_cast<const float4*>(hin + (size_t)s0i * SIN + c0);
                    const float4 q1 = *reinterpret_cast<const float4*>(hin + (size_t)s1i * SIN + c0);
                    const float4 q2 = *reinterpret_cast<const float4*>(hin + (size_t)s2i * SIN + c0);
                    const float4 q3 = *reinterpret_cast<const float4*>(hin + (size_t)s3i * SIN + c0);
                    s[0] = s[0] + (w0 * q0.x); s[1] = s[1] + (w0 * q0.y);
                    s[2] = s[2] + (w0 * q0.z); s[3] = s[3] + (w0 * q0.w);
                    s[0] = s[0] + (w1 * q1.x); s[1] = s[1] + (w1 * q1.y);
                    s[2] = s[2] + (w1 * q1.z); s[3] = s[3] + (w1 * q1.w);
                    s[0] = s[0] + (w2 * q2.x); s[1] = s[1] + (w2 * q2.y);
                    s[2] = s[2] + (w2 * q2.z); s[3] = s[3] + (w2 * q2.w);
                    s[0] = s[0] + (w3 * q3.x); s[1] = s[1] + (w3 * q3.y);
                    s[2] = s[2] + (w3 * q3.z); s[3] = s[3] + (w3 * q3.w);
                }
                for (; j < end; ++j) {
                    unsigned long long p = __builtin_nontemporal_load(&pk[j]);
                    int si;
                    float w;
                    unpack_edge(p, si, w);
                    const float4 q = *reinterpret_cast<const float4*>(hin + (size_t)si * SIN + c0);
                    s[0] = s[0] + (w * q.x); s[1] = s[1] + (w * q.y);
                    s[2] = s[2] + (w * q.z); s[3] = s[3] + (w * q.w);
                }
            } else {  // GS == 2
                for (; j + 3 < end; j += 4) {
                    unsigned long long p0 = __builtin_nontemporal_load(&pk[j]);
                    unsigned long long p1 = __builtin_nontemporal_load(&pk[j + 1]);
                    unsigned long long p2 = __builtin_nontemporal_load(&pk[j + 2]);
                    unsigned long long p3 = __builtin_nontemporal_load(&pk[j + 3]);
                    int s0i, s1i, s2i, s3i;
                    float w0, w1, w2, w3;
                    unpack_edge(p0, s0i, w0);
                    unpack_edge(p1, s1i, w1);
                    unpack_edge(p2, s2i, w2);
                    unpack_edge(p3, s3i, w3);
                    const float2 q0 = *reinterpret_cast<const float2*>(hin + (size_t)s0i * SIN + c0);
                    const float2 q1 = *reinterpret_cast<const float2*>(hin + (size_t)s1i * SIN + c0);
                    const float2 q2 = *reinterpret_cast<const float2*>(hin + (size_t)s2i * SIN + c0);
                    const float2 q3 = *reinterpret_cast<const float2*>(hin + (size_t)s3i * SIN + c0);
                    s[0] = s[0] + (w0 * q0.x); s[1] = s[1] + (w0 * q0.y);
                    s[0] = s[0] + (w1 * q1.x); s[1] = s[1] + (w1 * q1.y);
                    s[0] = s[0] + (w2 * q2.x); s[1] = s[1] + (w2 * q2.y);
                    s[0] = s[0] + (w3 * q3.x); s[1] = s[1] + (w3 * q3.y);
                }
                for (; j < end; ++j) {
                    unsigned long long p = __builtin_nontemporal_load(&pk[j]);
                    int si;
                    float w;
                    unpack_edge(p, si, w);
                    const float2 q = *reinterpret_cast<const float2*>(hin + (size_t)si * SIN + c0);
                    s[0] = s[0] + (w * q.x); s[1] = s[1] + (w * q.y);
                }
            }
            float t[GS];
            if (rec) {
#pragma unroll
                for (int g = 0; g < GS; ++g) t[g] = 2.f * s[g] - prev[(size_t)n * SIN + c0 + g];
            } else {
#pragma unroll
                for (int g = 0; g < GS; ++g) t[g] = s[g];
            }
#pragma unroll
            for (int g = 0; g < GS; ++g) tls[r][c0 + g] = t[g];
            if constexpr (GS == 4) {
                *reinterpret_cast<float4*>(tx_out + (size_t)n * SIN + c0) =
                    make_float4(t[0], t[1], t[2], t[3]);
            } else {
                *reinterpret_cast<float2*>(tx_out + (size_t)n * SIN + c0) =
                    make_float2(t[0], t[1]);
            }
        }
        __syncthreads();
        if (vn) {
            for (int co = lane; co < COUT; co += LANES) {
                float m = 0.f;
#pragma unroll
                for (int ci = 0; ci < CIN; ++ci) m = fmaf(tls[r][ci], Wk[ci * COUT + co], m);
                acc[(size_t)n * SACC + co] = acc[(size_t)n * SACC + co] + m;
            }
        }
    }
}

// a = silu(a + b) at padded stride S, real channels C only
template <int C, int S>
__global__ void silu_bias_kernel(float* __restrict__ a, const float* __restrict__ b) {
#pragma clang fp contract(off)
    {
        int t = blockIdx.x * blockDim.x + threadIdx.x;
        if (t >= N_NODES * C) return;
        int n = t / C, c = t - n * C;
        float x = a[(size_t)n * S + c] + b[c];
        float sig = 1.f / (1.f + expf(-x));
        a[(size_t)n * S + c] = x * sig;
    }
}

// out[n] = sigmoid(h[n,:27] @ W4), h at stride 28
__global__ void final_kernel(const float* __restrict__ h, const float* __restrict__ W4,
                             float* __restrict__ out) {
#pragma clang fp contract(off)
    {
        int n = blockIdx.x * blockDim.x + threadIdx.x;
        if (n >= N_NODES) return;
        const float* hr = h + (size_t)n * 28;
        float m = 0.f;
#pragma unroll
        for (int ci = 0; ci < 27; ++ci) m = fmaf(hr[ci], W4[ci], m);
        out[n] = 1.f / (1.f + expf(-m));
    }
}

__global__ void signal_kernel(float* __restrict__ out, float val) {
    int n = blockIdx.x * blockDim.x + threadIdx.x;
    if (n < N_NODES) out[n] = val;
}

// ==================== host driver ====================

static void run_scan(const int* cnt, int* bsums, int* rp, hipStream_t stream) {
    const int nb = (N_NODES + 1023) / 1024;  // 98
    scan_partial_kernel<<<nb, 256, 0, stream>>>(cnt, bsums);
    scan_bsums_kernel<<<1, 64, 0, stream>>>(bsums, nb, rp + N_NODES);
    scan_final_kernel<<<nb, 256, 0, stream>>>(cnt, bsums, rp);
}

template <int CIN, int COUT, int SIN, int SACC, int GS, int LANES, int R>
static void run_layer(int K, const float* hin, const float* W, float* acc, float* b0, float* b1,
                      float* b2, const int* rp, const unsigned long long* pk,
                      hipStream_t stream) {
    const int gInit = (N_NODES * COUT + BS - 1) / BS;
    const int gProp = (N_NODES + R - 1) / R;
    layer_init_kernel<CIN, COUT, SIN, SACC><<<gInit, BS, 0, stream>>>(hin, W, acc);
    if (K > 1) {
        float* bufs[3] = {b0, b1, b2};
        prop_mm_kernel<CIN, COUT, SIN, SACC, GS, LANES, R><<<gProp, LANES * R, 0, stream>>>(
            rp, pk, hin, nullptr, W + 1 * CIN * COUT, 0, bufs[0], acc);
        const float* pm2 = hin;      // tx_{k-2}
        const float* pm1 = bufs[0];  // tx_{k-1}
        for (int k = 2; k < K; ++k) {
            float* outb = bufs[(k - 1) % 3];  // k=2->b1, k=3->b2, k=4->b0, ...
            prop_mm_kernel<CIN, COUT, SIN, SACC, GS, LANES, R><<<gProp, LANES * R, 0, stream>>>(
                rp, pk, pm1, pm2, W + k * CIN * COUT, 1, outb, acc);
            pm2 = pm1;
            pm1 = outb;
        }
    }
}

extern "C" void kernel_launch(void* const* d_in, const int* in_sizes, int n_in, void* d_out,
                              int out_size, void* d_ws, size_t ws_size, hipStream_t stream) {
    const float* x  = (const float*)d_in[0];
    const int* idx  = (const int*)d_in[1];
    const float* ew = (const float*)d_in[2];
    const float* W1 = (const float*)d_in[3];
    const float* b1 = (const float*)d_in[4];
    const float* W2 = (const float*)d_in[5];
    const float* b2 = (const float*)d_in[6];
    const float* W3 = (const float*)d_in[7];
    const float* b3 = (const float*)d_in[8];
    const float* W4 = (const float*)d_in[9];
    float* out = (float*)d_out;
    (void)in_sizes; (void)n_in; (void)out_size;

    const int* src = idx;
    const int* dst = idx + N_EDGES;

    // workspace carve-up (256B aligned) — ~77.2 MB
    size_t off = 0;
    auto alloc = [&](size_t bytes) {
        size_t o = off;
        off = (off + bytes + 255) & ~(size_t)255;
        return o;
    };
    char* ws = (char*)d_ws;
    int*   cnt_s   = (int*)(ws + alloc(N_NODES * 4));          // src counts -> fill cursors
    int*   cnt_d   = (int*)(ws + alloc(N_NODES * 4));          // dst counts -> fill cursors
    int*   rp_src  = (int*)(ws + alloc((N_NODES + 1) * 4));
    int*   rp_dst  = (int*)(ws + alloc((N_NODES + 1) * 4));
    float* dis     = (float*)(ws + alloc(N_NODES * 4));
    int*   bsums   = (int*)(ws + alloc(512));
    int2*  packed  = (int2*)(ws + alloc((size_t)N_EDGES * 8));
    // layer-phase pool (49.6 MB, contiguous). Setup aliases carved from its base:
    const size_t pool_off = alloc(0);
    float* t0      = (float*)(ws + alloc((size_t)N_NODES * 20 * 4));  // tx, stride<=20
    float* t1      = (float*)(ws + alloc((size_t)N_NODES * 20 * 4));
    float* t2      = (float*)(ws + alloc((size_t)N_NODES * 20 * 4));
    float* accA    = (float*)(ws + alloc((size_t)N_NODES * 16 * 4));  // L1 out, stride 16
    float* accB    = (float*)(ws + alloc((size_t)N_NODES * 20 * 4));  // L2 out, stride 20
    float* accC    = (float*)(ws + alloc((size_t)N_NODES * 28 * 4));  // L3 out, stride 28
    const size_t NEED = off;
    // setup-only aliases inside the pool (49.6MB; each raw array is 12.8MB):
    // raw_s @ +0, raw_d @ +16MB — disjoint; pool first written by layer phase.
    char* pool = ws + pool_off;
    int* raw_s = (int*)(pool);
    int* raw_d = (int*)(pool + ((size_t)16 << 20));

    int gE = (N_EDGES + BS - 1) / BS;
    int gN = (N_NODES + BS - 1) / BS;

    if (ws_size < NEED) {  // diagnostic: reveal ws_size as 6000+MB in absmax
        signal_kernel<<<gN, BS, 0, stream>>>(
            out, 6000.0f + (float)(ws_size / (1024.0 * 1024.0)));
        return;
    }

    // ---- fused setup ----
    (void)hipMemsetAsync(cnt_s, 0, N_NODES * 4, stream);
    (void)hipMemsetAsync(cnt_d, 0, N_NODES * 4, stream);
    count2_kernel<<<gE, BS, 0, stream>>>(src, dst, cnt_s, cnt_d);
    run_scan(cnt_s, bsums, rp_src, stream);
    run_scan(cnt_d, bsums, rp_dst, stream);
    (void)hipMemcpyAsync(cnt_s, rp_src, N_NODES * 4, hipMemcpyDeviceToDevice, stream);
    (void)hipMemcpyAsync(cnt_d, rp_dst, N_NODES * 4, hipMemcpyDeviceToDevice, stream);
    fill2_kernel<<<gE, BS, 0, stream>>>(src, dst, cnt_s, cnt_d, raw_s, raw_d);
    sort_deg_kernel<<<gN, BS, 0, stream>>>(rp_src, raw_s, ew, dis);
    sort_fill_dst_kernel<<<gN, BS, 0, stream>>>(rp_dst, raw_d, src, ew, dis, packed);

    const unsigned long long* pk = (const unsigned long long*)packed;

    // ---- layers ----
    // L1: CIN=2 (x, stride 2), out accA stride 16; 1 lane x 256 rows (float2 gather)
    run_layer<2, 14, 2, 16, 2, 1, 256>(39, x, W1, accA, t0, t1, t2, rp_dst, pk, stream);
    silu_bias_kernel<14, 16><<<(N_NODES * 14 + BS - 1) / BS, BS, 0, stream>>>(accA, b1);
    // L2: CIN=14 @ stride 16 (64B rows), out accB stride 20; 4 lanes x 64 rows
    run_layer<14, 20, 16, 20, 4, 4, 64>(43, accA, W2, accB, t0, t1, t2, rp_dst, pk, stream);
    silu_bias_kernel<20, 20><<<(N_NODES * 20 + BS - 1) / BS, BS, 0, stream>>>(accB, b2);
    // L3: CIN=20 @ stride 20 (PACKED 8MB), out accC stride 28; 5 lanes x 51 rows
    run_layer<20, 27, 20, 28, 4, 5, 51>(45, accB, W3, accC, t0, t1, t2, rp_dst, pk, stream);
    silu_bias_kernel<27, 28><<<(N_NODES * 27 + BS - 1) / BS, BS, 0, stream>>>(accC, b3);
    final_kernel<<<gN, BS, 0, stream>>>(accC, W4, out);
}

// Round 15
// 9109.335 us; speedup vs baseline: 1.2402x; 1.2402x over previous
//
#include <hip/hip_runtime.h>
#include <math.h>

#define N_NODES 100000
#define N_EDGES 3200000
#define BS 256

// ==================== setup: deterministic CSR construction ====================
// All-f32 data path, rounding-matched to the numpy reference (absmax 8.4e-11,
// rounds 7-14):
//  - bucket sums in ascending edge-id order (np.add.at semantics)
//  - products rounded separately from adds in the SpMV (np: norm*h then add.at)
//  - matmuls as ascending-k fmaf chains from 0, then one add
//  - dis = 1/sqrtf
// f64 is provably WRONG here (4 distinct f64 impls -> absmax 0.9999987).
// EVERY fp chain must stay bit-identical under refactors: parallelize only
// across independent chains (channels, rows), never within one.
//
// Perf model (r9-r14): props are bound by random 64B h-sector traffic through
// L2/L3 (~205MB/dispatch, ~3.4TB/s effective). Gathered state must stay PACKED
// (r11: footprint > alignment). NEVER nontemporal on pk: it is re-read by all
// 124 dispatches and normally L3-resident — NT pushed it to HBM, +2.3ms (r14,
// confirming r11). unroll-4 plain loads is the sweet spot (r13).

// one pass over edges: count both src and dst buckets
__global__ void count2_kernel(const int* __restrict__ src, const int* __restrict__ dst,
                              int* __restrict__ cnt_s, int* __restrict__ cnt_d) {
    int e = blockIdx.x * blockDim.x + threadIdx.x;
    if (e < N_EDGES) {
        atomicAdd(&cnt_s[src[e]], 1);
        atomicAdd(&cnt_d[dst[e]], 1);
    }
}

__global__ void scan_partial_kernel(const int* __restrict__ cnt, int* __restrict__ bsums) {
    __shared__ int lds[256];
    int tid = threadIdx.x;
    int base = blockIdx.x * 1024 + tid * 4;
    int s = 0;
#pragma unroll
    for (int i = 0; i < 4; ++i) s += (base + i < N_NODES) ? cnt[base + i] : 0;
    lds[tid] = s;
    __syncthreads();
    for (int off = 128; off > 0; off >>= 1) {
        if (tid < off) lds[tid] += lds[tid + off];
        __syncthreads();
    }
    if (tid == 0) bsums[blockIdx.x] = lds[0];
}

__global__ void scan_bsums_kernel(int* __restrict__ bsums, int nb, int* __restrict__ total_out) {
    if (threadIdx.x == 0 && blockIdx.x == 0) {
        int acc = 0;
        for (int b = 0; b < nb; ++b) {
            int v = bsums[b];
            bsums[b] = acc;
            acc += v;
        }
        *total_out = acc;
    }
}

__global__ void scan_final_kernel(const int* __restrict__ cnt, const int* __restrict__ bsums,
                                  int* __restrict__ rp) {
    __shared__ int lds[256];
    int tid = threadIdx.x;
    int base = blockIdx.x * 1024 + tid * 4;
    int v[4];
    int ts = 0;
#pragma unroll
    for (int i = 0; i < 4; ++i) {
        v[i] = (base + i < N_NODES) ? cnt[base + i] : 0;
        ts += v[i];
    }
    lds[tid] = ts;
    __syncthreads();
    for (int off = 1; off < 256; off <<= 1) {
        int t = (tid >= off) ? lds[tid - off] : 0;
        __syncthreads();
        lds[tid] += t;
        __syncthreads();
    }
    int run = lds[tid] - ts + bsums[blockIdx.x];
#pragma unroll
    for (int i = 0; i < 4; ++i) {
        if (base + i < N_NODES) rp[base + i] = run;
        run += v[i];
    }
}

// one pass over edges: scatter edge ids into both src- and dst-keyed buckets
__global__ void fill2_kernel(const int* __restrict__ src, const int* __restrict__ dst,
                             int* __restrict__ fill_s, int* __restrict__ fill_d,
                             int* __restrict__ raw_s, int* __restrict__ raw_d) {
    int e = blockIdx.x * blockDim.x + threadIdx.x;
    if (e >= N_EDGES) return;
    int slot_s = atomicAdd(&fill_s[src[e]], 1);
    raw_s[slot_s] = e;
    int slot_d = atomicAdd(&fill_d[dst[e]], 1);
    raw_d[slot_d] = e;
}

// fused src-side: deg[n] = sum of w over row n in ASCENDING EDGE-ID order
// (selection walk, O(d^2) like the rank sort it replaces), then dis = 1/sqrtf.
__global__ void sort_deg_kernel(const int* __restrict__ rp_src, const int* __restrict__ raw,
                                const float* __restrict__ w, float* __restrict__ dis) {
#pragma clang fp contract(off)
    {
        int n = blockIdx.x * blockDim.x + threadIdx.x;
        if (n >= N_NODES) return;
        int beg = rp_src[n], end = rp_src[n + 1];
        float d = 0.f;
        int last = -1;
        for (int t = beg; t < end; ++t) {
            int mn = 0x7fffffff;
            for (int j = beg; j < end; ++j) {
                int e = raw[j];
                if (e > last && e < mn) mn = e;
            }
            d = d + w[mn];
            last = mn;
        }
        dis[n] = (d > 0.f) ? (1.0f / sqrtf(d)) : 0.f;
    }
}

// fused dst-side: rank-sort by edge id writes the packed CSR entry directly.
// packed[beg+rank] = {src, ((-dis[s]) * w) * dis[n]}  (n == dst of the row)
__global__ void sort_fill_dst_kernel(const int* __restrict__ rp_dst, const int* __restrict__ raw,
                                     const int* __restrict__ src, const float* __restrict__ w,
                                     const float* __restrict__ dis, int2* __restrict__ packed) {
#pragma clang fp contract(off)
    {
        int n = blockIdx.x * blockDim.x + threadIdx.x;
        if (n >= N_NODES) return;
        int beg = rp_dst[n], end = rp_dst[n + 1];
        float dn = dis[n];
        for (int i = beg; i < end; ++i) {
            int e = raw[i];
            int r = 0;
            for (int j = beg; j < end; ++j) r += (raw[j] < e);
            int s = src[e];
            float cw = ((-dis[s]) * w[e]) * dn;
            packed[beg + r] = make_int2(s, __float_as_int(cw));
        }
    }
}

// ==================== per-layer kernels (f32, rounding-matched) ====================

// thread per (n,co): acc[n*SACC+co] = fmaf-chain over ci of hin[n*SIN+ci]*W0[ci,co]
template <int CIN, int COUT, int SIN, int SACC>
__global__ void layer_init_kernel(const float* __restrict__ hin, const float* __restrict__ W0,
                                  float* __restrict__ acc) {
    int t = blockIdx.x * blockDim.x + threadIdx.x;
    if (t >= N_NODES * COUT) return;
    int n = t / COUT, co = t - n * COUT;
    const float* hr = hin + (size_t)n * SIN;
    float m = 0.f;
#pragma unroll
    for (int ci = 0; ci < CIN; ++ci) m = fmaf(hr[ci], W0[ci * COUT + co], m);
    acc[(size_t)n * SACC + co] = m;
}

// Grouped-channel prop+matmul. Block = R rows x LANES lanes; lane owns GS
// consecutive channels (GS=4 -> one aligned float4 gather/edge; GS=2 -> float2).
// Per-channel gather chains in ascending edge-id order (mul rounded then add);
// recurrence; LDS handoff; ascending-ci fmaf matmul chain; acc += m.
// Edge loop unrolled x4 with PLAIN loads (pk must stay cacheable!): 4 edge
// records + 4 gathers issue before the order-preserved add chains.
template <int CIN, int COUT, int SIN, int SACC, int GS, int LANES, int R>
__global__ __launch_bounds__(LANES* R) void prop_mm_kernel(
    const int* __restrict__ rp, const int2* __restrict__ pk, const float* __restrict__ hin,
    const float* __restrict__ prev, const float* __restrict__ Wk, int rec,
    float* __restrict__ tx_out, float* __restrict__ acc) {
#pragma clang fp contract(off)
    {
        __shared__ float tls[R][LANES * GS];
        int r = threadIdx.x / LANES;
        int lane = threadIdx.x - r * LANES;
        int n = blockIdx.x * R + r;
        bool vn = (n < N_NODES);
        if (vn) {
            int c0 = lane * GS;
            float s[GS];
#pragma unroll
            for (int g = 0; g < GS; ++g) s[g] = 0.f;
            int beg = rp[n], end = rp[n + 1];
            int j = beg;
            if constexpr (GS == 4) {
                for (; j + 3 < end; j += 4) {
                    int2 p0 = pk[j];
                    int2 p1 = pk[j + 1];
                    int2 p2 = pk[j + 2];
                    int2 p3 = pk[j + 3];
                    const float4 q0 = *reinterpret_cast<const float4*>(hin + (size_t)p0.x * SIN + c0);
                    const float4 q1 = *reinterpret_cast<const float4*>(hin + (size_t)p1.x * SIN + c0);
                    const float4 q2 = *reinterpret_cast<const float4*>(hin + (size_t)p2.x * SIN + c0);
                    const float4 q3 = *reinterpret_cast<const float4*>(hin + (size_t)p3.x * SIN + c0);
                    float w0 = __int_as_float(p0.y), w1 = __int_as_float(p1.y);
                    float w2 = __int_as_float(p2.y), w3 = __int_as_float(p3.y);
                    s[0] = s[0] + (w0 * q0.x); s[1] = s[1] + (w0 * q0.y);
                    s[2] = s[2] + (w0 * q0.z); s[3] = s[3] + (w0 * q0.w);
                    s[0] = s[0] + (w1 * q1.x); s[1] = s[1] + (w1 * q1.y);
                    s[2] = s[2] + (w1 * q1.z); s[3] = s[3] + (w1 * q1.w);
                    s[0] = s[0] + (w2 * q2.x); s[1] = s[1] + (w2 * q2.y);
                    s[2] = s[2] + (w2 * q2.z); s[3] = s[3] + (w2 * q2.w);
                    s[0] = s[0] + (w3 * q3.x); s[1] = s[1] + (w3 * q3.y);
                    s[2] = s[2] + (w3 * q3.z); s[3] = s[3] + (w3 * q3.w);
                }
                for (; j < end; ++j) {
                    int2 p = pk[j];
                    float w = __int_as_float(p.y);
                    const float4 q = *reinterpret_cast<const float4*>(hin + (size_t)p.x * SIN + c0);
                    s[0] = s[0] + (w * q.x); s[1] = s[1] + (w * q.y);
                    s[2] = s[2] + (w * q.z); s[3] = s[3] + (w * q.w);
                }
            } else {  // GS == 2
                for (; j + 3 < end; j += 4) {
                    int2 p0 = pk[j];
                    int2 p1 = pk[j + 1];
                    int2 p2 = pk[j + 2];
                    int2 p3 = pk[j + 3];
                    const float2 q0 = *reinterpret_cast<const float2*>(hin + (size_t)p0.x * SIN + c0);
                    const float2 q1 = *reinterpret_cast<const float2*>(hin + (size_t)p1.x * SIN + c0);
                    const float2 q2 = *reinterpret_cast<const float2*>(hin + (size_t)p2.x * SIN + c0);
                    const float2 q3 = *reinterpret_cast<const float2*>(hin + (size_t)p3.x * SIN + c0);
                    float w0 = __int_as_float(p0.y), w1 = __int_as_float(p1.y);
                    float w2 = __int_as_float(p2.y), w3 = __int_as_float(p3.y);
                    s[0] = s[0] + (w0 * q0.x); s[1] = s[1] + (w0 * q0.y);
                    s[0] = s[0] + (w1 * q1.x); s[1] = s[1] + (w1 * q1.y);
                    s[0] = s[0] + (w2 * q2.x); s[1] = s[1] + (w2 * q2.y);
                    s[0] = s[0] + (w3 * q3.x); s[1] = s[1] + (w3 * q3.y);
                }
                for (; j < end; ++j) {
                    int2 p = pk[j];
                    float w = __int_as_float(p.y);
                    const float2 q = *reinterpret_cast<const float2*>(hin + (size_t)p.x * SIN + c0);
                    s[0] = s[0] + (w * q.x); s[1] = s[1] + (w * q.y);
                }
            }
            float t[GS];
            if (rec) {
#pragma unroll
                for (int g = 0; g < GS; ++g) t[g] = 2.f * s[g] - prev[(size_t)n * SIN + c0 + g];
            } else {
#pragma unroll
                for (int g = 0; g < GS; ++g) t[g] = s[g];
            }
#pragma unroll
            for (int g = 0; g < GS; ++g) tls[r][c0 + g] = t[g];
            if constexpr (GS == 4) {
                *reinterpret_cast<float4*>(tx_out + (size_t)n * SIN + c0) =
                    make_float4(t[0], t[1], t[2], t[3]);
            } else {
                *reinterpret_cast<float2*>(tx_out + (size_t)n * SIN + c0) =
                    make_float2(t[0], t[1]);
            }
        }
        __syncthreads();
        if (vn) {
            for (int co = lane; co < COUT; co += LANES) {
                float m = 0.f;
#pragma unroll
                for (int ci = 0; ci < CIN; ++ci) m = fmaf(tls[r][ci], Wk[ci * COUT + co], m);
                acc[(size_t)n * SACC + co] = acc[(size_t)n * SACC + co] + m;
            }
        }
    }
}

// a = silu(a + b) at padded stride S, real channels C only
template <int C, int S>
__global__ void silu_bias_kernel(float* __restrict__ a, const float* __restrict__ b) {
#pragma clang fp contract(off)
    {
        int t = blockIdx.x * blockDim.x + threadIdx.x;
        if (t >= N_NODES * C) return;
        int n = t / C, c = t - n * C;
        float x = a[(size_t)n * S + c] + b[c];
        float sig = 1.f / (1.f + expf(-x));
        a[(size_t)n * S + c] = x * sig;
    }
}

// out[n] = sigmoid(h[n,:27] @ W4), h at stride 28
__global__ void final_kernel(const float* __restrict__ h, const float* __restrict__ W4,
                             float* __restrict__ out) {
#pragma clang fp contract(off)
    {
        int n = blockIdx.x * blockDim.x + threadIdx.x;
        if (n >= N_NODES) return;
        const float* hr = h + (size_t)n * 28;
        float m = 0.f;
#pragma unroll
        for (int ci = 0; ci < 27; ++ci) m = fmaf(hr[ci], W4[ci], m);
        out[n] = 1.f / (1.f + expf(-m));
    }
}

__global__ void signal_kernel(float* __restrict__ out, float val) {
    int n = blockIdx.x * blockDim.x + threadIdx.x;
    if (n < N_NODES) out[n] = val;
}

// ==================== host driver ====================

static void run_scan(const int* cnt, int* bsums, int* rp, hipStream_t stream) {
    const int nb = (N_NODES + 1023) / 1024;  // 98
    scan_partial_kernel<<<nb, 256, 0, stream>>>(cnt, bsums);
    scan_bsums_kernel<<<1, 64, 0, stream>>>(bsums, nb, rp + N_NODES);
    scan_final_kernel<<<nb, 256, 0, stream>>>(cnt, bsums, rp);
}

template <int CIN, int COUT, int SIN, int SACC, int GS, int LANES, int R>
static void run_layer(int K, const float* hin, const float* W, float* acc, float* b0, float* b1,
                      float* b2, const int* rp, const int2* pk, hipStream_t stream) {
    const int gInit = (N_NODES * COUT + BS - 1) / BS;
    const int gProp = (N_NODES + R - 1) / R;
    layer_init_kernel<CIN, COUT, SIN, SACC><<<gInit, BS, 0, stream>>>(hin, W, acc);
    if (K > 1) {
        float* bufs[3] = {b0, b1, b2};
        prop_mm_kernel<CIN, COUT, SIN, SACC, GS, LANES, R><<<gProp, LANES * R, 0, stream>>>(
            rp, pk, hin, nullptr, W + 1 * CIN * COUT, 0, bufs[0], acc);
        const float* pm2 = hin;      // tx_{k-2}
        const float* pm1 = bufs[0];  // tx_{k-1}
        for (int k = 2; k < K; ++k) {
            float* outb = bufs[(k - 1) % 3];  // k=2->b1, k=3->b2, k=4->b0, ...
            prop_mm_kernel<CIN, COUT, SIN, SACC, GS, LANES, R><<<gProp, LANES * R, 0, stream>>>(
                rp, pk, pm1, pm2, W + k * CIN * COUT, 1, outb, acc);
            pm2 = pm1;
            pm1 = outb;
        }
    }
}

extern "C" void kernel_launch(void* const* d_in, const int* in_sizes, int n_in, void* d_out,
                              int out_size, void* d_ws, size_t ws_size, hipStream_t stream) {
    const float* x  = (const float*)d_in[0];
    const int* idx  = (const int*)d_in[1];
    const float* ew = (const float*)d_in[2];
    const float* W1 = (const float*)d_in[3];
    const float* b1 = (const float*)d_in[4];
    const float* W2 = (const float*)d_in[5];
    const float* b2 = (const float*)d_in[6];
    const float* W3 = (const float*)d_in[7];
    const float* b3 = (const float*)d_in[8];
    const float* W4 = (const float*)d_in[9];
    float* out = (float*)d_out;
    (void)in_sizes; (void)n_in; (void)out_size;

    const int* src = idx;
    const int* dst = idx + N_EDGES;

    // workspace carve-up (256B aligned) — ~77.2 MB
    size_t off = 0;
    auto alloc = [&](size_t bytes) {
        size_t o = off;
        off = (off + bytes + 255) & ~(size_t)255;
        return o;
    };
    char* ws = (char*)d_ws;
    int*   cnt_s   = (int*)(ws + alloc(N_NODES * 4));          // src counts -> fill cursors
    int*   cnt_d   = (int*)(ws + alloc(N_NODES * 4));          // dst counts -> fill cursors
    int*   rp_src  = (int*)(ws + alloc((N_NODES + 1) * 4));
    int*   rp_dst  = (int*)(ws + alloc((N_NODES + 1) * 4));
    float* dis     = (float*)(ws + alloc(N_NODES * 4));
    int*   bsums   = (int*)(ws + alloc(512));
    int2*  packed  = (int2*)(ws + alloc((size_t)N_EDGES * 8));
    // layer-phase pool (49.6 MB, contiguous). Setup aliases carved from its base:
    const size_t pool_off = alloc(0);
    float* t0      = (float*)(ws + alloc((size_t)N_NODES * 20 * 4));  // tx, stride<=20
    float* t1      = (float*)(ws + alloc((size_t)N_NODES * 20 * 4));
    float* t2      = (float*)(ws + alloc((size_t)N_NODES * 20 * 4));
    float* accA    = (float*)(ws + alloc((size_t)N_NODES * 16 * 4));  // L1 out, stride 16
    float* accB    = (float*)(ws + alloc((size_t)N_NODES * 20 * 4));  // L2 out, stride 20
    float* accC    = (float*)(ws + alloc((size_t)N_NODES * 28 * 4));  // L3 out, stride 28
    const size_t NEED = off;
    // setup-only aliases inside the pool (49.6MB; each raw array is 12.8MB):
    // raw_s @ +0, raw_d @ +16MB — disjoint; pool first written by layer phase.
    char* pool = ws + pool_off;
    int* raw_s = (int*)(pool);
    int* raw_d = (int*)(pool + ((size_t)16 << 20));

    int gE = (N_EDGES + BS - 1) / BS;
    int gN = (N_NODES + BS - 1) / BS;

    if (ws_size < NEED) {  // diagnostic: reveal ws_size as 6000+MB in absmax
        signal_kernel<<<gN, BS, 0, stream>>>(
            out, 6000.0f + (float)(ws_size / (1024.0 * 1024.0)));
        return;
    }

    // ---- fused setup ----
    (void)hipMemsetAsync(cnt_s, 0, N_NODES * 4, stream);
    (void)hipMemsetAsync(cnt_d, 0, N_NODES * 4, stream);
    count2_kernel<<<gE, BS, 0, stream>>>(src, dst, cnt_s, cnt_d);
    run_scan(cnt_s, bsums, rp_src, stream);
    run_scan(cnt_d, bsums, rp_dst, stream);
    (void)hipMemcpyAsync(cnt_s, rp_src, N_NODES * 4, hipMemcpyDeviceToDevice, stream);
    (void)hipMemcpyAsync(cnt_d, rp_dst, N_NODES * 4, hipMemcpyDeviceToDevice, stream);
    fill2_kernel<<<gE, BS, 0, stream>>>(src, dst, cnt_s, cnt_d, raw_s, raw_d);
    sort_deg_kernel<<<gN, BS, 0, stream>>>(rp_src, raw_s, ew, dis);
    sort_fill_dst_kernel<<<gN, BS, 0, stream>>>(rp_dst, raw_d, src, ew, dis, packed);

    // ---- layers ----
    // L1: CIN=2 (x, stride 2), out accA stride 16; 1 lane x 256 rows (float2 gather)
    run_layer<2, 14, 2, 16, 2, 1, 256>(39, x, W1, accA, t0, t1, t2, rp_dst, packed, stream);
    silu_bias_kernel<14, 16><<<(N_NODES * 14 + BS - 1) / BS, BS, 0, stream>>>(accA, b1);
    // L2: CIN=14 @ stride 16 (64B rows), out accB stride 20; 4 lanes x 64 rows
    run_layer<14, 20, 16, 20, 4, 4, 64>(43, accA, W2, accB, t0, t1, t2, rp_dst, packed, stream);
    silu_bias_kernel<20, 20><<<(N_NODES * 20 + BS - 1) / BS, BS, 0, stream>>>(accB, b2);
    // L3: CIN=20 @ stride 20 (PACKED 8MB), out accC stride 28; 5 lanes x 51 rows
    run_layer<20, 27, 20, 28, 4, 5, 51>(45, accB, W3, accC, t0, t1, t2, rp_dst, packed, stream);
    silu_bias_kernel<27, 28><<<(N_NODES * 27 + BS - 1) / BS, BS, 0, stream>>>(accC, b3);
    final_kernel<<<gN, BS, 0, stream>>>(accC, W4, out);
}

// Round 16
// 8980.875 us; speedup vs baseline: 1.2579x; 1.0143x over previous
//
#include <hip/hip_runtime.h>
#include <math.h>

#define N_NODES 100000
#define N_EDGES 3200000
#define BS 256

// ==================== setup: deterministic CSR construction ====================
// All-f32 data path, rounding-matched to the numpy reference (absmax 8.4e-11,
// rounds 7-15):
//  - bucket sums in ascending edge-id order (np.add.at semantics)
//  - products rounded separately from adds in the SpMV (np: norm*h then add.at)
//  - matmuls as ascending-k fmaf chains from 0, then one add
//  - dis = 1/sqrtf
// f64 is provably WRONG here (4 distinct f64 impls -> absmax 0.9999987).
// EVERY fp chain must stay bit-identical under refactors: parallelize only
// across independent chains (channels, rows), never within one.
//
// Final perf model (r9-r15 A/Bs): props are bound by INTRINSIC random 64B
// h-sector traffic (~205MB/dispatch, no over-fetch) at the ~3.4TB/s effective
// L2/L3 scatter rate -> ~7.2ms across 124 dispatches. Setup ~1.3ms (fill2's
// 414MB = write-allocate amplification intrinsic to random scatter).
// Lever outcomes: unroll-4 KEEP (+250us); fused count2/fill2 KEEP (~300us);
// packed strides KEEP (r11: footprint > alignment, 35%); NT-on-pk NEVER
// (r14: +2.3ms — pk is L3-resident and re-read 124x); fused sorts REVERTED
// (r15: selection-walk heavier than rank-sort+consume, +150us).

// one pass over edges: count both src and dst buckets
__global__ void count2_kernel(const int* __restrict__ src, const int* __restrict__ dst,
                              int* __restrict__ cnt_s, int* __restrict__ cnt_d) {
    int e = blockIdx.x * blockDim.x + threadIdx.x;
    if (e < N_EDGES) {
        atomicAdd(&cnt_s[src[e]], 1);
        atomicAdd(&cnt_d[dst[e]], 1);
    }
}

__global__ void scan_partial_kernel(const int* __restrict__ cnt, int* __restrict__ bsums) {
    __shared__ int lds[256];
    int tid = threadIdx.x;
    int base = blockIdx.x * 1024 + tid * 4;
    int s = 0;
#pragma unroll
    for (int i = 0; i < 4; ++i) s += (base + i < N_NODES) ? cnt[base + i] : 0;
    lds[tid] = s;
    __syncthreads();
    for (int off = 128; off > 0; off >>= 1) {
        if (tid < off) lds[tid] += lds[tid + off];
        __syncthreads();
    }
    if (tid == 0) bsums[blockIdx.x] = lds[0];
}

__global__ void scan_bsums_kernel(int* __restrict__ bsums, int nb, int* __restrict__ total_out) {
    if (threadIdx.x == 0 && blockIdx.x == 0) {
        int acc = 0;
        for (int b = 0; b < nb; ++b) {
            int v = bsums[b];
            bsums[b] = acc;
            acc += v;
        }
        *total_out = acc;
    }
}

__global__ void scan_final_kernel(const int* __restrict__ cnt, const int* __restrict__ bsums,
                                  int* __restrict__ rp) {
    __shared__ int lds[256];
    int tid = threadIdx.x;
    int base = blockIdx.x * 1024 + tid * 4;
    int v[4];
    int ts = 0;
#pragma unroll
    for (int i = 0; i < 4; ++i) {
        v[i] = (base + i < N_NODES) ? cnt[base + i] : 0;
        ts += v[i];
    }
    lds[tid] = ts;
    __syncthreads();
    for (int off = 1; off < 256; off <<= 1) {
        int t = (tid >= off) ? lds[tid - off] : 0;
        __syncthreads();
        lds[tid] += t;
        __syncthreads();
    }
    int run = lds[tid] - ts + bsums[blockIdx.x];
#pragma unroll
    for (int i = 0; i < 4; ++i) {
        if (base + i < N_NODES) rp[base + i] = run;
        run += v[i];
    }
}

// one pass over edges: scatter edge ids into both src- and dst-keyed buckets
__global__ void fill2_kernel(const int* __restrict__ src, const int* __restrict__ dst,
                             int* __restrict__ fill_s, int* __restrict__ fill_d,
                             int* __restrict__ raw_s, int* __restrict__ raw_d) {
    int e = blockIdx.x * blockDim.x + threadIdx.x;
    if (e >= N_EDGES) return;
    int slot_s = atomicAdd(&fill_s[src[e]], 1);
    raw_s[slot_s] = e;
    int slot_d = atomicAdd(&fill_d[dst[e]], 1);
    raw_d[slot_d] = e;
}

// per-row rank-selection sort by edge id: deterministic final layout
__global__ void sort_rows_kernel(const int* __restrict__ rp, const int* __restrict__ raw,
                                 int* __restrict__ sorted) {
    int n = blockIdx.x * blockDim.x + threadIdx.x;
    if (n >= N_NODES) return;
    int beg = rp[n], end = rp[n + 1];
    for (int i = beg; i < end; ++i) {
        int v = raw[i];
        int r = 0;
        for (int j = beg; j < end; ++j) r += (raw[j] < v);
        sorted[beg + r] = v;
    }
}

// dis[n] = 1/sqrtf(f32 sum of w over src-row n, ascending edge id), 0 if deg<=0
__global__ void deg_dis_kernel(const int* __restrict__ rp_src, const int* __restrict__ sorted,
                               const float* __restrict__ w, float* __restrict__ dis) {
#pragma clang fp contract(off)
    {
        int n = blockIdx.x * blockDim.x + threadIdx.x;
        if (n >= N_NODES) return;
        float d = 0.f;
        int beg = rp_src[n], end = rp_src[n + 1];
        for (int j = beg; j < end; ++j) d = d + w[sorted[j]];
        dis[n] = (d > 0.f) ? (1.0f / sqrtf(d)) : 0.f;
    }
}

// packed[j] = {src, ((-dis[s]) * w) * dis[d]}
__global__ void csr_fill_kernel(const int* __restrict__ sorted, const int* __restrict__ src,
                                const int* __restrict__ dst, const float* __restrict__ w,
                                const float* __restrict__ dis, int2* __restrict__ packed) {
#pragma clang fp contract(off)
    {
        int j = blockIdx.x * blockDim.x + threadIdx.x;
        if (j >= N_EDGES) return;
        int e = sorted[j];
        int s = src[e], d = dst[e];
        float cw = ((-dis[s]) * w[e]) * dis[d];
        packed[j] = make_int2(s, __float_as_int(cw));
    }
}

// ==================== per-layer kernels (f32, rounding-matched) ====================

// thread per (n,co): acc[n*SACC+co] = fmaf-chain over ci of hin[n*SIN+ci]*W0[ci,co]
template <int CIN, int COUT, int SIN, int SACC>
__global__ void layer_init_kernel(const float* __restrict__ hin, const float* __restrict__ W0,
                                  float* __restrict__ acc) {
    int t = blockIdx.x * blockDim.x + threadIdx.x;
    if (t >= N_NODES * COUT) return;
    int n = t / COUT, co = t - n * COUT;
    const float* hr = hin + (size_t)n * SIN;
    float m = 0.f;
#pragma unroll
    for (int ci = 0; ci < CIN; ++ci) m = fmaf(hr[ci], W0[ci * COUT + co], m);
    acc[(size_t)n * SACC + co] = m;
}

// Grouped-channel prop+matmul. Block = R rows x LANES lanes; lane owns GS
// consecutive channels (GS=4 -> one aligned float4 gather/edge; GS=2 -> float2).
// Per-channel gather chains in ascending edge-id order (mul rounded then add);
// recurrence; LDS handoff; ascending-ci fmaf matmul chain; acc += m.
// Edge loop unrolled x4 with PLAIN loads (pk must stay cacheable!): 4 edge
// records + 4 gathers issue before the order-preserved add chains.
template <int CIN, int COUT, int SIN, int SACC, int GS, int LANES, int R>
__global__ __launch_bounds__(LANES* R) void prop_mm_kernel(
    const int* __restrict__ rp, const int2* __restrict__ pk, const float* __restrict__ hin,
    const float* __restrict__ prev, const float* __restrict__ Wk, int rec,
    float* __restrict__ tx_out, float* __restrict__ acc) {
#pragma clang fp contract(off)
    {
        __shared__ float tls[R][LANES * GS];
        int r = threadIdx.x / LANES;
        int lane = threadIdx.x - r * LANES;
        int n = blockIdx.x * R + r;
        bool vn = (n < N_NODES);
        if (vn) {
            int c0 = lane * GS;
            float s[GS];
#pragma unroll
            for (int g = 0; g < GS; ++g) s[g] = 0.f;
            int beg = rp[n], end = rp[n + 1];
            int j = beg;
            if constexpr (GS == 4) {
                for (; j + 3 < end; j += 4) {
                    int2 p0 = pk[j];
                    int2 p1 = pk[j + 1];
                    int2 p2 = pk[j + 2];
                    int2 p3 = pk[j + 3];
                    const float4 q0 = *reinterpret_cast<const float4*>(hin + (size_t)p0.x * SIN + c0);
                    const float4 q1 = *reinterpret_cast<const float4*>(hin + (size_t)p1.x * SIN + c0);
                    const float4 q2 = *reinterpret_cast<const float4*>(hin + (size_t)p2.x * SIN + c0);
                    const float4 q3 = *reinterpret_cast<const float4*>(hin + (size_t)p3.x * SIN + c0);
                    float w0 = __int_as_float(p0.y), w1 = __int_as_float(p1.y);
                    float w2 = __int_as_float(p2.y), w3 = __int_as_float(p3.y);
                    s[0] = s[0] + (w0 * q0.x); s[1] = s[1] + (w0 * q0.y);
                    s[2] = s[2] + (w0 * q0.z); s[3] = s[3] + (w0 * q0.w);
                    s[0] = s[0] + (w1 * q1.x); s[1] = s[1] + (w1 * q1.y);
                    s[2] = s[2] + (w1 * q1.z); s[3] = s[3] + (w1 * q1.w);
                    s[0] = s[0] + (w2 * q2.x); s[1] = s[1] + (w2 * q2.y);
                    s[2] = s[2] + (w2 * q2.z); s[3] = s[3] + (w2 * q2.w);
                    s[0] = s[0] + (w3 * q3.x); s[1] = s[1] + (w3 * q3.y);
                    s[2] = s[2] + (w3 * q3.z); s[3] = s[3] + (w3 * q3.w);
                }
                for (; j < end; ++j) {
                    int2 p = pk[j];
                    float w = __int_as_float(p.y);
                    const float4 q = *reinterpret_cast<const float4*>(hin + (size_t)p.x * SIN + c0);
                    s[0] = s[0] + (w * q.x); s[1] = s[1] + (w * q.y);
                    s[2] = s[2] + (w * q.z); s[3] = s[3] + (w * q.w);
                }
            } else {  // GS == 2
                for (; j + 3 < end; j += 4) {
                    int2 p0 = pk[j];
                    int2 p1 = pk[j + 1];
                    int2 p2 = pk[j + 2];
                    int2 p3 = pk[j + 3];
                    const float2 q0 = *reinterpret_cast<const float2*>(hin + (size_t)p0.x * SIN + c0);
                    const float2 q1 = *reinterpret_cast<const float2*>(hin + (size_t)p1.x * SIN + c0);
                    const float2 q2 = *reinterpret_cast<const float2*>(hin + (size_t)p2.x * SIN + c0);
                    const float2 q3 = *reinterpret_cast<const float2*>(hin + (size_t)p3.x * SIN + c0);
                    float w0 = __int_as_float(p0.y), w1 = __int_as_float(p1.y);
                    float w2 = __int_as_float(p2.y), w3 = __int_as_float(p3.y);
                    s[0] = s[0] + (w0 * q0.x); s[1] = s[1] + (w0 * q0.y);
                    s[0] = s[0] + (w1 * q1.x); s[1] = s[1] + (w1 * q1.y);
                    s[0] = s[0] + (w2 * q2.x); s[1] = s[1] + (w2 * q2.y);
                    s[0] = s[0] + (w3 * q3.x); s[1] = s[1] + (w3 * q3.y);
                }
                for (; j < end; ++j) {
                    int2 p = pk[j];
                    float w = __int_as_float(p.y);
                    const float2 q = *reinterpret_cast<const float2*>(hin + (size_t)p.x * SIN + c0);
                    s[0] = s[0] + (w * q.x); s[1] = s[1] + (w * q.y);
                }
            }
            float t[GS];
            if (rec) {
#pragma unroll
                for (int g = 0; g < GS; ++g) t[g] = 2.f * s[g] - prev[(size_t)n * SIN + c0 + g];
            } else {
#pragma unroll
                for (int g = 0; g < GS; ++g) t[g] = s[g];
            }
#pragma unroll
            for (int g = 0; g < GS; ++g) tls[r][c0 + g] = t[g];
            if constexpr (GS == 4) {
                *reinterpret_cast<float4*>(tx_out + (size_t)n * SIN + c0) =
                    make_float4(t[0], t[1], t[2], t[3]);
            } else {
                *reinterpret_cast<float2*>(tx_out + (size_t)n * SIN + c0) =
                    make_float2(t[0], t[1]);
            }
        }
        __syncthreads();
        if (vn) {
            for (int co = lane; co < COUT; co += LANES) {
                float m = 0.f;
#pragma unroll
                for (int ci = 0; ci < CIN; ++ci) m = fmaf(tls[r][ci], Wk[ci * COUT + co], m);
                acc[(size_t)n * SACC + co] = acc[(size_t)n * SACC + co] + m;
            }
        }
    }
}

// a = silu(a + b) at padded stride S, real channels C only
template <int C, int S>
__global__ void silu_bias_kernel(float* __restrict__ a, const float* __restrict__ b) {
#pragma clang fp contract(off)
    {
        int t = blockIdx.x * blockDim.x + threadIdx.x;
        if (t >= N_NODES * C) return;
        int n = t / C, c = t - n * C;
        float x = a[(size_t)n * S + c] + b[c];
        float sig = 1.f / (1.f + expf(-x));
        a[(size_t)n * S + c] = x * sig;
    }
}

// out[n] = sigmoid(h[n,:27] @ W4), h at stride 28
__global__ void final_kernel(const float* __restrict__ h, const float* __restrict__ W4,
                             float* __restrict__ out) {
#pragma clang fp contract(off)
    {
        int n = blockIdx.x * blockDim.x + threadIdx.x;
        if (n >= N_NODES) return;
        const float* hr = h + (size_t)n * 28;
        float m = 0.f;
#pragma unroll
        for (int ci = 0; ci < 27; ++ci) m = fmaf(hr[ci], W4[ci], m);
        out[n] = 1.f / (1.f + expf(-m));
    }
}

__global__ void signal_kernel(float* __restrict__ out, float val) {
    int n = blockIdx.x * blockDim.x + threadIdx.x;
    if (n < N_NODES) out[n] = val;
}

// ==================== host driver ====================

static void run_scan(const int* cnt, int* bsums, int* rp, hipStream_t stream) {
    const int nb = (N_NODES + 1023) / 1024;  // 98
    scan_partial_kernel<<<nb, 256, 0, stream>>>(cnt, bsums);
    scan_bsums_kernel<<<1, 64, 0, stream>>>(bsums, nb, rp + N_NODES);
    scan_final_kernel<<<nb, 256, 0, stream>>>(cnt, bsums, rp);
}

template <int CIN, int COUT, int SIN, int SACC, int GS, int LANES, int R>
static void run_layer(int K, const float* hin, const float* W, float* acc, float* b0, float* b1,
                      float* b2, const int* rp, const int2* pk, hipStream_t stream) {
    const int gInit = (N_NODES * COUT + BS - 1) / BS;
    const int gProp = (N_NODES + R - 1) / R;
    layer_init_kernel<CIN, COUT, SIN, SACC><<<gInit, BS, 0, stream>>>(hin, W, acc);
    if (K > 1) {
        float* bufs[3] = {b0, b1, b2};
        prop_mm_kernel<CIN, COUT, SIN, SACC, GS, LANES, R><<<gProp, LANES * R, 0, stream>>>(
            rp, pk, hin, nullptr, W + 1 * CIN * COUT, 0, bufs[0], acc);
        const float* pm2 = hin;      // tx_{k-2}
        const float* pm1 = bufs[0];  // tx_{k-1}
        for (int k = 2; k < K; ++k) {
            float* outb = bufs[(k - 1) % 3];  // k=2->b1, k=3->b2, k=4->b0, ...
            prop_mm_kernel<CIN, COUT, SIN, SACC, GS, LANES, R><<<gProp, LANES * R, 0, stream>>>(
                rp, pk, pm1, pm2, W + k * CIN * COUT, 1, outb, acc);
            pm2 = pm1;
            pm1 = outb;
        }
    }
}

extern "C" void kernel_launch(void* const* d_in, const int* in_sizes, int n_in, void* d_out,
                              int out_size, void* d_ws, size_t ws_size, hipStream_t stream) {
    const float* x  = (const float*)d_in[0];
    const int* idx  = (const int*)d_in[1];
    const float* ew = (const float*)d_in[2];
    const float* W1 = (const float*)d_in[3];
    const float* b1 = (const float*)d_in[4];
    const float* W2 = (const float*)d_in[5];
    const float* b2 = (const float*)d_in[6];
    const float* W3 = (const float*)d_in[7];
    const float* b3 = (const float*)d_in[8];
    const float* W4 = (const float*)d_in[9];
    float* out = (float*)d_out;
    (void)in_sizes; (void)n_in; (void)out_size;

    const int* src = idx;
    const int* dst = idx + N_EDGES;

    // workspace carve-up (256B aligned) — ~77.2 MB
    size_t off = 0;
    auto alloc = [&](size_t bytes) {
        size_t o = off;
        off = (off + bytes + 255) & ~(size_t)255;
        return o;
    };
    char* ws = (char*)d_ws;
    int*   cnt_s   = (int*)(ws + alloc(N_NODES * 4));          // src counts -> fill cursors
    int*   cnt_d   = (int*)(ws + alloc(N_NODES * 4));          // dst counts -> fill cursors
    int*   rp_src  = (int*)(ws + alloc((N_NODES + 1) * 4));
    int*   rp_dst  = (int*)(ws + alloc((N_NODES + 1) * 4));
    float* dis     = (float*)(ws + alloc(N_NODES * 4));
    int*   bsums   = (int*)(ws + alloc(512));
    int2*  packed  = (int2*)(ws + alloc((size_t)N_EDGES * 8));
    // layer-phase pool (49.6 MB, contiguous). Setup aliases carved from its base:
    const size_t pool_off = alloc(0);
    float* t0      = (float*)(ws + alloc((size_t)N_NODES * 20 * 4));  // tx, stride<=20
    float* t1      = (float*)(ws + alloc((size_t)N_NODES * 20 * 4));
    float* t2      = (float*)(ws + alloc((size_t)N_NODES * 20 * 4));
    float* accA    = (float*)(ws + alloc((size_t)N_NODES * 16 * 4));  // L1 out, stride 16
    float* accB    = (float*)(ws + alloc((size_t)N_NODES * 20 * 4));  // L2 out, stride 20
    float* accC    = (float*)(ws + alloc((size_t)N_NODES * 28 * 4));  // L3 out, stride 28
    const size_t NEED = off;
    // setup-only aliases inside the pool (49.6MB; each array is 12.8MB):
    // raw_s @ +0, raw_d @ +16MB, sorted_s @ +32MB; sorted_d reuses +0 after
    // raw_s's last read (sort_s). All disjoint; pool first written by layers.
    char* pool = ws + pool_off;
    int* raw_s    = (int*)(pool);
    int* raw_d    = (int*)(pool + ((size_t)16 << 20));
    int* sorted_s = (int*)(pool + ((size_t)32 << 20));
    int* sorted_d = (int*)(pool);

    int gE = (N_EDGES + BS - 1) / BS;
    int gN = (N_NODES + BS - 1) / BS;

    if (ws_size < NEED) {  // diagnostic: reveal ws_size as 6000+MB in absmax
        signal_kernel<<<gN, BS, 0, stream>>>(
            out, 6000.0f + (float)(ws_size / (1024.0 * 1024.0)));
        return;
    }

    // ---- fused setup: one edge pass for both counts, one for both fills ----
    (void)hipMemsetAsync(cnt_s, 0, N_NODES * 4, stream);
    (void)hipMemsetAsync(cnt_d, 0, N_NODES * 4, stream);
    count2_kernel<<<gE, BS, 0, stream>>>(src, dst, cnt_s, cnt_d);
    run_scan(cnt_s, bsums, rp_src, stream);
    run_scan(cnt_d, bsums, rp_dst, stream);
    (void)hipMemcpyAsync(cnt_s, rp_src, N_NODES * 4, hipMemcpyDeviceToDevice, stream);
    (void)hipMemcpyAsync(cnt_d, rp_dst, N_NODES * 4, hipMemcpyDeviceToDevice, stream);
    fill2_kernel<<<gE, BS, 0, stream>>>(src, dst, cnt_s, cnt_d, raw_s, raw_d);
    sort_rows_kernel<<<gN, BS, 0, stream>>>(rp_src, raw_s, sorted_s);
    deg_dis_kernel<<<gN, BS, 0, stream>>>(rp_src, sorted_s, ew, dis);
    sort_rows_kernel<<<gN, BS, 0, stream>>>(rp_dst, raw_d, sorted_d);
    csr_fill_kernel<<<gE, BS, 0, stream>>>(sorted_d, src, dst, ew, dis, packed);

    // ---- layers ----
    // L1: CIN=2 (x, stride 2), out accA stride 16; 1 lane x 256 rows (float2 gather)
    run_layer<2, 14, 2, 16, 2, 1, 256>(39, x, W1, accA, t0, t1, t2, rp_dst, packed, stream);
    silu_bias_kernel<14, 16><<<(N_NODES * 14 + BS - 1) / BS, BS, 0, stream>>>(accA, b1);
    // L2: CIN=14 @ stride 16 (64B rows), out accB stride 20; 4 lanes x 64 rows
    run_layer<14, 20, 16, 20, 4, 4, 64>(43, accA, W2, accB, t0, t1, t2, rp_dst, packed, stream);
    silu_bias_kernel<20, 20><<<(N_NODES * 20 + BS - 1) / BS, BS, 0, stream>>>(accB, b2);
    // L3: CIN=20 @ stride 20 (PACKED 8MB), out accC stride 28; 5 lanes x 51 rows
    run_layer<20, 27, 20, 28, 4, 5, 51>(45, accB, W3, accC, t0, t1, t2, rp_dst, packed, stream);
    silu_bias_kernel<27, 28><<<(N_NODES * 27 + BS - 1) / BS, BS, 0, stream>>>(accC, b3);
    final_kernel<<<gN, BS, 0, stream>>>(accC, W4, out);
}